// Round 1
// baseline (269.637 us; speedup 1.0000x reference)
//
#include <hip/hip_runtime.h>

// MemoryBank contrastive loss, steady state.
// B=1024, D=128, C=50, K=4096, N = C*K = 204800. TEMP=0.3.
// loss = (1/B) * sum_b w_b * ( ln(sum_{c,k} exp(dot(feat_b, mem_ck)/T)) - dot(feat_b, mem_{lab,0})/T )
//
// Trick: fold SCALE = log2(e)/T into normalized features (pre-bf16), so the
// MFMA accumulator t = sims*log2(e) feeds exp2 directly:
//   S_b = sum 2^t ;  loss_b = ln2 * (log2(S_b) - t_pos)

#define BDIM 256
#define TILE_N 64
#define NITER 16           // n-tiles per block; 204800/64/16 = 200 chunks
#define LN2f 0.6931471805599453f
#define SCALEf 4.808983469629878f   // log2(e)/0.3

typedef __attribute__((ext_vector_type(8))) short bf16x8;
typedef __attribute__((ext_vector_type(4))) float f32x4;

__device__ __forceinline__ unsigned short f2bf(float x) {
    union { float f; unsigned int u; } c; c.f = x;
    unsigned int u = c.u;
    u = (u + 0x7fffu + ((u >> 16) & 1u)) >> 16;   // round-to-nearest-even
    return (unsigned short)u;
}
__device__ __forceinline__ float bf2f(unsigned short h) {
    union { unsigned int u; float f; } c; c.u = ((unsigned int)h) << 16;
    return c.f;
}

// ---------------- Kernel 1: normalize features, scale, cast to bf16 ----------
__global__ void normalize_feat(const float* __restrict__ f,
                               unsigned short* __restrict__ featb) {
    const int b = blockIdx.x;          // 1024 blocks
    const int t = threadIdx.x;         // 128 threads (2 waves)
    float v = f[b * 128 + t];
    float ss = v * v;
    #pragma unroll
    for (int m = 1; m < 64; m <<= 1) ss += __shfl_xor(ss, m, 64);
    __shared__ float wsum[2];
    if ((t & 63) == 0) wsum[t >> 6] = ss;
    __syncthreads();
    float tot = wsum[0] + wsum[1];
    float inv = SCALEf / fmaxf(sqrtf(tot), 1e-12f);
    featb[b * 128 + t] = f2bf(v * inv);
}

// ---------------- Kernel 2: fused GEMM + exp2-sum ----------------------------
// Block tile: 256 (m) x 64 (n), K=128 complete. 4 waves; wave w owns m-slice
// [w*64, w*64+64). A-frags (scaled bf16 feat) held in registers for all NITER
// n-tiles. B-tile staged fp32->bf16 into padded LDS each iteration.
__global__ __launch_bounds__(BDIM, 2) void gemm_lse(
        const unsigned short* __restrict__ featb,  // [1024][128] bf16
        const float* __restrict__ mem,             // [204800][128] fp32
        float* __restrict__ S)                     // [1024] exp-sums
{
    __shared__ unsigned short ldsb[TILE_N * 136];  // row stride 136 (+8 pad)

    const int tid  = threadIdx.x;
    const int wave = tid >> 6;
    const int lane = tid & 63;
    const int col  = lane & 15;
    const int quad = lane >> 4;

    const int m_base = blockIdx.y * 256 + wave * 64;

    // A fragments: A[m=lane&15][k=quad*8+j], 4 m-frags x 4 k-steps
    bf16x8 afrag[4][4];
    #pragma unroll
    for (int mf = 0; mf < 4; ++mf)
        #pragma unroll
        for (int ks = 0; ks < 4; ++ks)
            afrag[mf][ks] = *(const bf16x8*)&featb[(size_t)(m_base + mf * 16 + col) * 128
                                                   + ks * 32 + quad * 8];

    float s_part[16];
    #pragma unroll
    for (int i = 0; i < 16; ++i) s_part[i] = 0.0f;

    const int tile0 = blockIdx.x * NITER;
    for (int t = 0; t < NITER; ++t) {
        const int n_base = (tile0 + t) * TILE_N;

        __syncthreads();   // previous tile's LDS reads done
        // stage 64x128 fp32 -> bf16 LDS (2048 float4 loads across 256 threads)
        const float4* src = (const float4*)(mem + (size_t)n_base * 128);
        #pragma unroll
        for (int i = 0; i < 8; ++i) {
            int g = i * 256 + tid;
            float4 v = src[g];
            int n = g >> 5;
            int k = (g & 31) * 4;
            ushort4 h;
            h.x = f2bf(v.x); h.y = f2bf(v.y); h.z = f2bf(v.z); h.w = f2bf(v.w);
            *(ushort4*)&ldsb[n * 136 + k] = h;
        }
        __syncthreads();

        f32x4 acc[4][4];
        #pragma unroll
        for (int mf = 0; mf < 4; ++mf)
            #pragma unroll
            for (int nf = 0; nf < 4; ++nf)
                acc[mf][nf] = (f32x4)(0.0f);

        #pragma unroll
        for (int ks = 0; ks < 4; ++ks) {
            bf16x8 bfrag[4];   // B^T[n=lane&15][k=quad*8+j]
            #pragma unroll
            for (int nf = 0; nf < 4; ++nf)
                bfrag[nf] = *(const bf16x8*)&ldsb[(nf * 16 + col) * 136 + ks * 32 + quad * 8];
            #pragma unroll
            for (int mf = 0; mf < 4; ++mf)
                #pragma unroll
                for (int nf = 0; nf < 4; ++nf)
                    acc[mf][nf] = __builtin_amdgcn_mfma_f32_16x16x32_bf16(
                        afrag[mf][ks], bfrag[nf], acc[mf][nf], 0, 0, 0);
        }

        // epilogue: accumulate 2^t per owned row (row = quad*4+r within m-frag)
        #pragma unroll
        for (int mf = 0; mf < 4; ++mf)
            #pragma unroll
            for (int nf = 0; nf < 4; ++nf)
                #pragma unroll
                for (int r = 0; r < 4; ++r)
                    s_part[mf * 4 + r] += exp2f(acc[mf][nf][r]);
    }

    // reduce across the 16 lanes (col dimension) sharing the same quad
    #pragma unroll
    for (int d = 1; d < 16; d <<= 1)
        #pragma unroll
        for (int i = 0; i < 16; ++i)
            s_part[i] += __shfl_xor(s_part[i], d, 64);

    if (col == 0) {
        #pragma unroll
        for (int i = 0; i < 16; ++i) {
            int row = m_base + (i >> 2) * 16 + quad * 4 + (i & 3);
            atomicAdd(&S[row], s_part[i]);
        }
    }
}

// ---------------- Kernel 3: pos logit + weighted mean ------------------------
__global__ void finalize_k(const unsigned short* __restrict__ featb,
                           const float* __restrict__ mem,
                           const int* __restrict__ labels,
                           const float* __restrict__ S,
                           float* __restrict__ out) {
    const int wave = threadIdx.x >> 6;
    const int lane = threadIdx.x & 63;
    const int b = blockIdx.x * 4 + wave;          // 256 blocks x 4 waves = 1024
    const int lab = labels[b];
    const float* mrow = mem + (size_t)lab * (4096 * 128);   // memory[lab][0][:]
    float fa = bf2f(featb[b * 128 + lane]);
    float fc = bf2f(featb[b * 128 + lane + 64]);
    float p = fa * mrow[lane] + fc * mrow[lane + 64];       // scaled-dot partial
    #pragma unroll
    for (int m = 1; m < 64; m <<= 1) p += __shfl_xor(p, m, 64);
    if (lane == 0) {
        float w = (lab < 2) ? 1.3f : 1.0f;
        float v = w * LN2f * (log2f(S[b]) - p) * (1.0f / 1024.0f);
        atomicAdd(out, v);
    }
}

extern "C" void kernel_launch(void* const* d_in, const int* in_sizes, int n_in,
                              void* d_out, int out_size, void* d_ws, size_t ws_size,
                              hipStream_t stream) {
    const float* features = (const float*)d_in[0];
    const int*   labels   = (const int*)d_in[1];
    const float* memory   = (const float*)d_in[2];
    float* out = (float*)d_out;

    unsigned short* featb = (unsigned short*)d_ws;               // 1024*128*2 = 256 KiB
    float* S = (float*)((char*)d_ws + 1024 * 128 * 2);           // 1024 floats

    hipMemsetAsync(S, 0, 1024 * sizeof(float), stream);
    hipMemsetAsync(out, 0, sizeof(float), stream);

    normalize_feat<<<1024, 128, 0, stream>>>(features, featb);
    gemm_lse<<<dim3(200, 4), BDIM, 0, stream>>>(featb, memory, S);
    finalize_k<<<256, 256, 0, stream>>>(featb, memory, labels, S, out);
}